// Round 5
// baseline (765.684 us; speedup 1.0000x reference)
//
#include <hip/hip_runtime.h>
#include <math.h>

typedef __attribute__((ext_vector_type(8))) unsigned short ushort8_t;
typedef __attribute__((ext_vector_type(8))) short bf16x8;
typedef __attribute__((ext_vector_type(4))) float f32x4;

namespace {

constexpr int Bn = 1024;
constexpr int Rn = 512;
constexpr int An = 196;
constexpr int Gn = 8192;     // P*4R
constexpr int Kcat = 1536;   // 3*R
constexpr int NP = 224;      // padded att cols per set (14 frags)
constexpr long ROWS = (long)Bn * An;  // 200704

__device__ __forceinline__ float b2f(unsigned short u) {
  union { unsigned int i; float f; } v; v.i = ((unsigned int)u) << 16; return v.f;
}
__device__ __forceinline__ unsigned short f2b(float f) {
  union { float f; unsigned int i; } v; v.f = f;
  unsigned int r = v.i + 0x7fffu + ((v.i >> 16) & 1u);
  return (unsigned short)(r >> 16);
}
__device__ __forceinline__ float sigmf(float x) {
  return __builtin_amdgcn_rcpf(1.f + __expf(-x));
}
__device__ __forceinline__ float tanhf_fast(float x) {
  const float e = __expf(2.f * x);
  return 1.f - 2.f * __builtin_amdgcn_rcpf(e + 1.f);
}

// ---- f32 -> bf16 copy, 8 elems/thread
__global__ __launch_bounds__(256)
void f2b_copy(const float* __restrict__ src, unsigned short* __restrict__ dst, long n)
{
  long i = ((long)blockIdx.x * 256 + threadIdx.x) * 8;
  const long stride = (long)gridDim.x * 256 * 8;
  for (; i + 8 <= n; i += stride) {
    float4 a = *(const float4*)(src + i);
    float4 b = *(const float4*)(src + i + 4);
    ushort8_t o;
    o[0] = f2b(a.x); o[1] = f2b(a.y); o[2] = f2b(a.z); o[3] = f2b(a.w);
    o[4] = f2b(b.x); o[5] = f2b(b.y); o[6] = f2b(b.z); o[7] = f2b(b.w);
    *(ushort8_t*)(dst + i) = o;
  }
}

// ---- pad+convert attention weights: Wp[2][NP][512] from Wa0/Wa1 [196][512]
__global__ __launch_bounds__(256)
void pack_wpad(const float* __restrict__ Wa0, const float* __restrict__ Wa1,
               unsigned short* __restrict__ Wp)
{
  long i = ((long)blockIdx.x * 256 + threadIdx.x) * 8;
  if (i >= 2L * NP * 512) return;
  const int set = (int)(i / (NP * 512));
  const int rem = (int)(i % (NP * 512));
  const int row = rem / 512, k = rem % 512;
  ushort8_t o;
  if (row < An) {
    const float* s = (set ? Wa1 : Wa0) + (long)row * 512 + k;
    float4 a = *(const float4*)s, b = *(const float4*)(s + 4);
    o[0] = f2b(a.x); o[1] = f2b(a.y); o[2] = f2b(a.z); o[3] = f2b(a.w);
    o[4] = f2b(b.x); o[5] = f2b(b.y); o[6] = f2b(b.z); o[7] = f2b(b.w);
  } else {
    o = ushort8_t{0,0,0,0,0,0,0,0};
  }
  *(ushort8_t*)(Wp + i) = o;
}

// ---- concat gate weights [8192][1536] bf16: [Wi | Wh | Wa]
__global__ __launch_bounds__(256)
void pack_w(const float* __restrict__ Wi, const float* __restrict__ Wh,
            const float* __restrict__ Wa, unsigned short* __restrict__ W2)
{
  long i = ((long)blockIdx.x * 256 + threadIdx.x) * 8;
  if (i >= (long)Gn * Kcat) return;
  const int g = (int)(i / Kcat);
  const int k = (int)(i % Kcat);
  const float* src = (k < 512) ? Wi + (long)g * 512 + k
                   : (k < 1024) ? Wh + (long)g * 512 + (k - 512)
                   : Wa + (long)g * 512 + (k - 1024);
  float4 a = *(const float4*)src;
  float4 b = *(const float4*)(src + 4);
  ushort8_t o;
  o[0] = f2b(a.x); o[1] = f2b(a.y); o[2] = f2b(a.z); o[3] = f2b(a.w);
  o[4] = f2b(b.x); o[5] = f2b(b.y); o[6] = f2b(b.z); o[7] = f2b(b.w);
  *(ushort8_t*)(W2 + i) = o;
}

// ---- concat gate inputs [1024][1536] bf16: [xa(+xb) | h | a]
__global__ __launch_bounds__(256)
void pack_x(const float* __restrict__ xa, const float* __restrict__ xb,
            const float* __restrict__ h, const float* __restrict__ a,
            unsigned short* __restrict__ X2)
{
  long i = ((long)blockIdx.x * 256 + threadIdx.x) * 8;
  if (i >= (long)Bn * Kcat) return;
  const int b = (int)(i / Kcat);
  const int k = (int)(i % Kcat);
  ushort8_t o;
  if (k < 512) {
    const float* s = xa + (long)b * 512 + k;
    float4 v0 = *(const float4*)s, v1 = *(const float4*)(s + 4);
    if (xb) {
      const float* s2 = xb + (long)b * 512 + k;
      float4 w0 = *(const float4*)s2, w1 = *(const float4*)(s2 + 4);
      v0.x += w0.x; v0.y += w0.y; v0.z += w0.z; v0.w += w0.w;
      v1.x += w1.x; v1.y += w1.y; v1.z += w1.z; v1.w += w1.w;
    }
    o[0] = f2b(v0.x); o[1] = f2b(v0.y); o[2] = f2b(v0.z); o[3] = f2b(v0.w);
    o[4] = f2b(v1.x); o[5] = f2b(v1.y); o[6] = f2b(v1.z); o[7] = f2b(v1.w);
  } else {
    const float* s = (k < 1024) ? h + (long)b * 512 + (k - 512)
                                : a + (long)b * 512 + (k - 1024);
    float4 v0 = *(const float4*)s, v1 = *(const float4*)(s + 4);
    o[0] = f2b(v0.x); o[1] = f2b(v0.y); o[2] = f2b(v0.z); o[3] = f2b(v0.w);
    o[4] = f2b(v1.x); o[5] = f2b(v1.y); o[6] = f2b(v1.z); o[7] = f2b(v1.w);
  }
  *(ushort8_t*)(X2 + i) = o;
}

// ---- fused dual-projection over att_bf rows (no global stores in K-loop).
// T[128 x 448] = att_bf * [Wa2a_pad | Wa2a1_pad]^T
// waves wc<2 (set0): dual first-attend score -> s0, s1
// waves wc>=2 (set1): av1(+bias) bf16 -> av_out
__global__ __launch_bounds__(512)
void av_both(const unsigned short* __restrict__ A,
             const unsigned short* __restrict__ Wcat,
             const float* __restrict__ b0vec, const float* __restrict__ b1vec,
             const float* __restrict__ Wd,
             const float* __restrict__ ah0, const float* __restrict__ ah1,
             float* __restrict__ s0, float* __restrict__ s1,
             unsigned short* __restrict__ av_out)
{
  constexpr int LDP = 56;   // 112B row stride: 28-bank step -> ~2-way (free)
  __shared__ unsigned short As[128 * LDP];
  __shared__ unsigned short Bs[448 * LDP];
  __shared__ float wds[NP], bas0[NP], bas1[NP];
  __shared__ float ahAs[128], ahBs[128];
  __shared__ float sbA[128], sbB[128];

  const int tid = threadIdx.x;
  const int lane = tid & 63, wid = tid >> 6;
  const int wr = wid >> 2, wc = wid & 3;          // 2 x 4 wave grid
  const int fr = lane & 15, q = lane >> 4, kg = q * 8;
  const long row0 = (long)blockIdx.x * 128;

  if (tid < NP) {
    bas0[tid] = (tid < An) ? b0vec[tid] : 0.f;
    bas1[tid] = (tid < An) ? b1vec[tid] : 0.f;
    wds[tid]  = (tid < An) ? Wd[tid] : 0.f;
  }
  if (tid >= 256 && tid < 384) {
    ahAs[tid - 256] = ah0[row0 + tid - 256];
    ahBs[tid - 256] = ah1[row0 + tid - 256];
  }

  f32x4 acc[4][7] = {};

  // A staging: thread t -> row t>>2, k-chunk (t&3)*8  (512 thr * 8 = 128*32)
  const int arow = tid >> 2, akc = (tid & 3) * 8;
  const unsigned short* Ap = A + (row0 + arow) * 512 + akc;
  // B staging: thread t<448 -> weight row t, 32 k per step
  const bool bload = tid < 448;
  const unsigned short* Bp = Wcat + (long)tid * 512;

  ushort8_t pa = *(const ushort8_t*)Ap;
  ushort8_t pb0{}, pb1{}, pb2{}, pb3{};
  if (bload) {
    pb0 = *(const ushort8_t*)(Bp);
    pb1 = *(const ushort8_t*)(Bp + 8);
    pb2 = *(const ushort8_t*)(Bp + 16);
    pb3 = *(const ushort8_t*)(Bp + 24);
  }
  const int swA = arow * LDP + akc;
  const int swB = tid * LDP;

  for (int kt = 0; kt < 512; kt += 32) {
    *(ushort8_t*)&As[swA] = pa;
    if (bload) {
      *(ushort8_t*)&Bs[swB] = pb0;
      *(ushort8_t*)&Bs[swB + 8] = pb1;
      *(ushort8_t*)&Bs[swB + 16] = pb2;
      *(ushort8_t*)&Bs[swB + 24] = pb3;
    }
    if (kt + 32 < 512) {
      pa = *(const ushort8_t*)(Ap + kt + 32);
      if (bload) {
        pb0 = *(const ushort8_t*)(Bp + kt + 32);
        pb1 = *(const ushort8_t*)(Bp + kt + 40);
        pb2 = *(const ushort8_t*)(Bp + kt + 48);
        pb3 = *(const ushort8_t*)(Bp + kt + 56);
      }
    }
    __syncthreads();
    bf16x8 af[4], bfr[7];
#pragma unroll
    for (int m = 0; m < 4; ++m)
      af[m] = *(const bf16x8*)&As[(wr * 64 + m * 16 + fr) * LDP + kg];
#pragma unroll
    for (int n = 0; n < 7; ++n)
      bfr[n] = *(const bf16x8*)&Bs[(wc * 112 + n * 16 + fr) * LDP + kg];
#pragma unroll
    for (int m = 0; m < 4; ++m)
#pragma unroll
      for (int n = 0; n < 7; ++n)
        acc[m][n] = __builtin_amdgcn_mfma_f32_16x16x32_bf16(af[m], bfr[n], acc[m][n], 0, 0, 0);
    __syncthreads();
  }

  float pA[4][4], pB[4][4];
#pragma unroll
  for (int m = 0; m < 4; ++m)
#pragma unroll
    for (int j = 0; j < 4; ++j) { pA[m][j] = 0.f; pB[m][j] = 0.f; }

  if (wc < 2) {
#pragma unroll
    for (int n = 0; n < 7; ++n) {
      const int col = wc * 112 + n * 16 + fr;
      const float wd = wds[col];
      const float bv = bas0[col];
#pragma unroll
      for (int m = 0; m < 4; ++m) {
#pragma unroll
        for (int j = 0; j < 4; ++j) {
          const int rl = wr * 64 + m * 16 + q * 4 + j;
          const float av = acc[m][n][j] + bv;
          pA[m][j] += wd * tanhf_fast(av + ahAs[rl]);
          pB[m][j] += wd * tanhf_fast(av + ahBs[rl]);
        }
      }
    }
#pragma unroll
    for (int m = 0; m < 4; ++m)
#pragma unroll
      for (int j = 0; j < 4; ++j) {
#pragma unroll
        for (int off = 1; off < 16; off <<= 1) {
          pA[m][j] += __shfl_xor(pA[m][j], off);
          pB[m][j] += __shfl_xor(pB[m][j], off);
        }
      }
  } else {
#pragma unroll
    for (int n = 0; n < 7; ++n) {
      const int col1 = (wc - 2) * 112 + n * 16 + fr;
      if (col1 >= An) continue;
      const float bv = bas1[col1];
#pragma unroll
      for (int m = 0; m < 4; ++m) {
#pragma unroll
        for (int j = 0; j < 4; ++j) {
          const long row = row0 + wr * 64 + m * 16 + q * 4 + j;
          av_out[row * An + col1] = f2b(acc[m][n][j] + bv);
        }
      }
    }
  }
  __syncthreads();
  if (wc == 0 && fr == 0) {
#pragma unroll
    for (int m = 0; m < 4; ++m)
#pragma unroll
      for (int j = 0; j < 4; ++j) {
        const int rl = wr * 64 + m * 16 + q * 4 + j;
        sbA[rl] = pA[m][j]; sbB[rl] = pB[m][j];
      }
  }
  __syncthreads();
  if (wc == 1 && fr == 0) {
#pragma unroll
    for (int m = 0; m < 4; ++m)
#pragma unroll
      for (int j = 0; j < 4; ++j) {
        const int rl = wr * 64 + m * 16 + q * 4 + j;
        sbA[rl] += pA[m][j]; sbB[rl] += pB[m][j];
      }
  }
  __syncthreads();
  if (tid < 128) {
    s0[row0 + tid] = sbA[tid];
    s1[row0 + tid] = sbB[tid];
  }
}

// ---- gate GEMM: C[1024,8192] = X2[1024,1536] * W2[8192,1536]^T + bias
// m97-style global_load_lds staging, linear LDS, 128x128 tile, BK=32.
__global__ __launch_bounds__(256)
void gemm_gate(const unsigned short* __restrict__ A, const unsigned short* __restrict__ Bm,
               const float* __restrict__ bias, float* __restrict__ C)
{
  __shared__ unsigned short As[128 * 32];
  __shared__ unsigned short Bs[128 * 32];
  const int tid = threadIdx.x;
  const int lane = tid & 63, w = tid >> 6;
  int bid = blockIdx.x;
  bid = (bid & 7) * (gridDim.x >> 3) + (bid >> 3);   // XCD-bijective (512 % 8 == 0)
  const int bx = bid & 63;          // 64 col tiles
  const int by = bid >> 6;          // 8 row tiles
  const long row0 = (long)by * 128;
  const long col0 = (long)bx * 128;
  const int wr = w >> 1, wc = w & 1;
  const int fr = lane & 15, q = lane >> 4;
  const int srow = lane >> 2, schk = lane & 3;   // staging: row within 16, 16B chunk

  f32x4 acc[4][4] = {};
  const unsigned short* A0 = A + row0 * Kcat + schk * 8;
  const unsigned short* B0 = Bm + col0 * Kcat + schk * 8;

  for (int kt = 0; kt < Kcat; kt += 32) {
#pragma unroll
    for (int i = 0; i < 2; ++i) {
      const int rr = (w * 2 + i) * 16 + srow;
      __builtin_amdgcn_global_load_lds(
          (const __attribute__((address_space(1))) unsigned int*)(A0 + (long)rr * Kcat + kt),
          (__attribute__((address_space(3))) unsigned int*)(As + (w * 2 + i) * 512),
          16, 0, 0);
      __builtin_amdgcn_global_load_lds(
          (const __attribute__((address_space(1))) unsigned int*)(B0 + (long)rr * Kcat + kt),
          (__attribute__((address_space(3))) unsigned int*)(Bs + (w * 2 + i) * 512),
          16, 0, 0);
    }
    __syncthreads();
    bf16x8 af[4], bfr[4];
#pragma unroll
    for (int m = 0; m < 4; ++m)
      af[m] = *(const bf16x8*)&As[(wr * 64 + m * 16 + fr) * 32 + q * 8];
#pragma unroll
    for (int n = 0; n < 4; ++n)
      bfr[n] = *(const bf16x8*)&Bs[(wc * 64 + n * 16 + fr) * 32 + q * 8];
#pragma unroll
    for (int m = 0; m < 4; ++m)
#pragma unroll
      for (int n = 0; n < 4; ++n)
        acc[m][n] = __builtin_amdgcn_mfma_f32_16x16x32_bf16(af[m], bfr[n], acc[m][n], 0, 0, 0);
    __syncthreads();
  }

  const int crow = wr * 64 + q * 4;
  const int ccol = wc * 64 + fr;
#pragma unroll
  for (int n = 0; n < 4; ++n) {
    const int col = (int)col0 + ccol + n * 16;
    const float bv = bias[col];
#pragma unroll
    for (int m = 0; m < 4; ++m) {
      const long rb = row0 + crow + m * 16;
#pragma unroll
      for (int j = 0; j < 4; ++j)
        C[(rb + j) * (long)Gn + col] = acc[m][n][j] + bv;
    }
  }
}

// ---- bf16 MFMA GEMM (small, ragged N): C[M,N] = A*B^T + bias, C f32
__global__ __launch_bounds__(256)
void gemm_bf(const unsigned short* __restrict__ A, const unsigned short* __restrict__ Bm,
             const float* __restrict__ bias, float* __restrict__ C,
             int N, int K, int ldc)
{
  constexpr int LDP = 56;
  __shared__ unsigned short As[128 * LDP];
  __shared__ unsigned short Bs[128 * LDP];
  const int tid = threadIdx.x;
  const long row0 = (long)blockIdx.y * 128;
  const int col0 = blockIdx.x * 128;
  const int wid = tid >> 6, lane = tid & 63;
  const int wr = wid >> 1, wc = wid & 1;
  const int fr = lane & 15, kg = (lane >> 4) * 8;

  f32x4 acc[4][4] = {};

  const int srow = tid >> 1;
  const int skh = tid & 1;
  const unsigned short* Ap = A + (row0 + srow) * (long)K + skh * 16;
  const int bcol = col0 + srow;
  const unsigned short* Bp = Bm + (long)(bcol < N ? bcol : N - 1) * K + skh * 16;

  ushort8_t a0 = *(const ushort8_t*)(Ap);
  ushort8_t a1 = *(const ushort8_t*)(Ap + 8);
  ushort8_t b0 = *(const ushort8_t*)(Bp);
  ushort8_t b1 = *(const ushort8_t*)(Bp + 8);

  const int sw = srow * LDP + skh * 16;
  for (int kt = 0; kt < K; kt += 32) {
    *(ushort8_t*)&As[sw] = a0;
    *(ushort8_t*)&As[sw + 8] = a1;
    *(ushort8_t*)&Bs[sw] = b0;
    *(ushort8_t*)&Bs[sw + 8] = b1;
    if (kt + 32 < K) {
      a0 = *(const ushort8_t*)(Ap + kt + 32);
      a1 = *(const ushort8_t*)(Ap + kt + 40);
      b0 = *(const ushort8_t*)(Bp + kt + 32);
      b1 = *(const ushort8_t*)(Bp + kt + 40);
    }
    __syncthreads();
    bf16x8 af[4], bfr[4];
#pragma unroll
    for (int m = 0; m < 4; ++m)
      af[m] = *(const bf16x8*)&As[(wr * 64 + m * 16 + fr) * LDP + kg];
#pragma unroll
    for (int n = 0; n < 4; ++n)
      bfr[n] = *(const bf16x8*)&Bs[(wc * 64 + n * 16 + fr) * LDP + kg];
#pragma unroll
    for (int m = 0; m < 4; ++m)
#pragma unroll
      for (int n = 0; n < 4; ++n)
        acc[m][n] = __builtin_amdgcn_mfma_f32_16x16x32_bf16(af[m], bfr[n], acc[m][n], 0, 0, 0);
    __syncthreads();
  }

  const int crow = wr * 64 + (lane >> 4) * 4;
  const int ccol = wc * 64 + fr;
#pragma unroll
  for (int n = 0; n < 4; ++n) {
    const int col = col0 + ccol + n * 16;
    if (col >= N) continue;
    const float bv = bias ? bias[col] : 0.f;
#pragma unroll
    for (int m = 0; m < 4; ++m) {
      const long rb = row0 + crow + m * 16;
#pragma unroll
      for (int j = 0; j < 4; ++j)
        C[(rb + j) * (long)ldc + col] = acc[m][n][j] + bv;
    }
  }
}

// ---- single score over cached bf16 av (raw, softmax happens in wsum)
__global__ __launch_bounds__(256)
void score1(const unsigned short* __restrict__ av, const float* __restrict__ ah,
            const float* __restrict__ Wd, float* __restrict__ s0)
{
  const int row = blockIdx.x * 4 + (threadIdx.x >> 6);
  const int lane = threadIdx.x & 63;
  const unsigned short* avp = av + (long)row * An;
  const float A0 = ah[row];
  float v0 = 0.f;
  for (int a = lane; a < An; a += 64)
    v0 += Wd[a] * tanhf_fast(b2f(avp[a]) + A0);
#pragma unroll
  for (int o = 32; o; o >>= 1) v0 += __shfl_down(v0, o);
  if (lane == 0) s0[row] = v0;
}

// ---- softmax (in-block) + weighted sum over bf16 att; 2 batches/block
template<bool DUAL>
__global__ __launch_bounds__(256)
void wsum2(const unsigned short* __restrict__ att,
           const float* __restrict__ w0, const float* __restrict__ w1,
           const float* __restrict__ add0,
           float* __restrict__ o0, float* __restrict__ o1)
{
  const int half = threadIdx.x >> 7;
  const int b = blockIdx.x * 2 + half;
  const int t = threadIdx.x & 127;
  const int wv = t >> 6;
  __shared__ float ws0[2][An], ws1[2][An];
  __shared__ float redm[2][2][2], redsum[2][2][2];  // [set][half][wave]

  // raw scores (2 elems/thread)
  const float r0a = w0[(long)b * An + t];
  const float r0b = (t + 128 < An) ? w0[(long)b * An + t + 128] : -3.0e38f;
  float r1a = -3.0e38f, r1b = -3.0e38f;
  if (DUAL) {
    r1a = w1[(long)b * An + t];
    r1b = (t + 128 < An) ? w1[(long)b * An + t + 128] : -3.0e38f;
  }
  float m0 = fmaxf(r0a, r0b), m1 = fmaxf(r1a, r1b);
#pragma unroll
  for (int o = 32; o; o >>= 1) {
    m0 = fmaxf(m0, __shfl_xor(m0, o));
    if (DUAL) m1 = fmaxf(m1, __shfl_xor(m1, o));
  }
  if ((t & 63) == 0) { redm[0][half][wv] = m0; if (DUAL) redm[1][half][wv] = m1; }
  __syncthreads();
  m0 = fmaxf(redm[0][half][0], redm[0][half][1]);
  if (DUAL) m1 = fmaxf(redm[1][half][0], redm[1][half][1]);
  const float e0a = __expf(r0a - m0);
  const float e0b = (t + 128 < An) ? __expf(r0b - m0) : 0.f;
  float sl0 = e0a + e0b, sl1 = 0.f;
  float e1a = 0.f, e1b = 0.f;
  if (DUAL) {
    e1a = __expf(r1a - m1);
    e1b = (t + 128 < An) ? __expf(r1b - m1) : 0.f;
    sl1 = e1a + e1b;
  }
#pragma unroll
  for (int o = 32; o; o >>= 1) {
    sl0 += __shfl_xor(sl0, o);
    if (DUAL) sl1 += __shfl_xor(sl1, o);
  }
  if ((t & 63) == 0) { redsum[0][half][wv] = sl0; if (DUAL) redsum[1][half][wv] = sl1; }
  __syncthreads();
  const float inv0 = __builtin_amdgcn_rcpf(redsum[0][half][0] + redsum[0][half][1]);
  ws0[half][t] = e0a * inv0;
  if (t + 128 < An) ws0[half][t + 128] = e0b * inv0;
  if (DUAL) {
    const float inv1 = __builtin_amdgcn_rcpf(redsum[1][half][0] + redsum[1][half][1]);
    ws1[half][t] = e1a * inv1;
    if (t + 128 < An) ws1[half][t + 128] = e1b * inv1;
  }
  __syncthreads();

  const unsigned short* ap = att + (long)b * An * Rn + t * 4;
  float a00 = 0, a01 = 0, a02 = 0, a03 = 0;
  float a10 = 0, a11 = 0, a12 = 0, a13 = 0;
  for (int s = 0; s < An; ++s) {
    ushort4 u = *(const ushort4*)(ap + (long)s * Rn);
    const float f0 = b2f(u.x), f1 = b2f(u.y), f2 = b2f(u.z), f3 = b2f(u.w);
    const float v0 = ws0[half][s];
    a00 = fmaf(f0, v0, a00); a01 = fmaf(f1, v0, a01);
    a02 = fmaf(f2, v0, a02); a03 = fmaf(f3, v0, a03);
    if (DUAL) {
      const float v1 = ws1[half][s];
      a10 = fmaf(f0, v1, a10); a11 = fmaf(f1, v1, a11);
      a12 = fmaf(f2, v1, a12); a13 = fmaf(f3, v1, a13);
    }
  }
  const long base = (long)b * Rn + t * 4;
  if (add0) {
    float4 ad = *(const float4*)(add0 + base);
    a00 += ad.x; a01 += ad.y; a02 += ad.z; a03 += ad.w;
  }
  *(float4*)(o0 + base) = make_float4(a00, a01, a02, a03);
  if (DUAL) *(float4*)(o1 + base) = make_float4(a10, a11, a12, a13);
}

// ---- LSTM pointwise over P=4 parallels
__global__ __launch_bounds__(256)
void gates_pw(const float* __restrict__ sums, const float* __restrict__ prev_c,
              float* __restrict__ out_c, float* __restrict__ nh,
              unsigned short* __restrict__ nh_bf)
{
  const int i = blockIdx.x * 256 + threadIdx.x;
  const int b = i >> 9;
  const int r = i & 511;
  const float c = prev_c[i];
  float aC = 0.f, aH = 0.f;
#pragma unroll
  for (int p = 0; p < 4; ++p) {
    const float* sp = sums + (long)b * Gn + p * 2048 + r;
    const float ig = sigmf(sp[0]);
    const float fg = sigmf(sp[512]);
    const float og = sigmf(sp[1024]);
    const float it = tanhf_fast(sp[1536]);
    const float nc = fmaf(fg, c, ig * it);
    aC += nc;
    aH = fmaf(og, tanhf_fast(nc), aH);
  }
  out_c[i] = aC * 0.25f;
  const float hv = aH * 0.25f;
  nh[i] = hv;
  nh_bf[i] = f2b(hv);
}

__global__ __launch_bounds__(256)
void bias3(const float* __restrict__ a, const float* __restrict__ b,
           const float* __restrict__ c, float* __restrict__ o, int n)
{
  const int i = blockIdx.x * 256 + threadIdx.x;
  if (i < n) o[i] = a[i] + b[i] + c[i];
}

} // namespace

extern "C" void kernel_launch(void* const* d_in, const int* in_sizes, int n_in,
                              void* d_out, int out_size, void* d_ws, size_t ws_size,
                              hipStream_t stream)
{
  const float* x      = (const float*)d_in[0];
  const float* att    = (const float*)d_in[1];
  const float* inputs = (const float*)d_in[2];
  const float* Wa2a   = (const float*)d_in[3];
  const float* ba2a   = (const float*)d_in[4];
  const float* Wh2a   = (const float*)d_in[5];
  const float* bh2a   = (const float*)d_in[6];
  const float* Wd2d   = (const float*)d_in[7];
  const float* Wa2a1  = (const float*)d_in[9];
  const float* ba2a1  = (const float*)d_in[10];
  const float* Wh2a1  = (const float*)d_in[11];
  const float* bh2a1  = (const float*)d_in[12];
  const float* Wd2d1  = (const float*)d_in[13];
  const float* Wi2h   = (const float*)d_in[15];
  const float* bi2h   = (const float*)d_in[16];
  const float* Wh2h   = (const float*)d_in[17];
  const float* bh2h   = (const float*)d_in[18];
  const float* Wa2h   = (const float*)d_in[19];
  const float* ba2h   = (const float*)d_in[20];
  (void)in_sizes; (void)n_in; (void)out_size; (void)ws_size;

  float* out = (float*)d_out;
  const float* prev_c0 = inputs + 0 * (long)Bn * Rn;
  const float* prev_h0 = inputs + 1 * (long)Bn * Rn;
  const float* prev_c1 = inputs + 2 * (long)Bn * Rn;
  const float* prev_h1 = inputs + 3 * (long)Bn * Rn;

  char* wsp = (char*)d_ws;
  size_t off = 0;
  auto alloc = [&](size_t bytes) -> void* {
    void* p = wsp + off;
    off += (bytes + 1023) & ~(size_t)1023;
    return p;
  };
  unsigned short* att_bf  = (unsigned short*)alloc(ROWS * Rn * 2);
  unsigned short* W2      = (unsigned short*)alloc((size_t)Gn * Kcat * 2);
  unsigned short* Wpad    = (unsigned short*)alloc((size_t)2 * NP * Rn * 2);
  unsigned short* wh2a_bf = (unsigned short*)alloc((size_t)An * Rn * 2);
  unsigned short* wh2a1_bf= (unsigned short*)alloc((size_t)An * Rn * 2);
  unsigned short* h0_bf   = (unsigned short*)alloc((size_t)Bn * Rn * 2);
  unsigned short* h1_bf   = (unsigned short*)alloc((size_t)Bn * Rn * 2);
  unsigned short* nh_bf   = (unsigned short*)alloc((size_t)Bn * Rn * 2);
  unsigned short* X2      = (unsigned short*)alloc((size_t)Bn * Kcat * 2);
  unsigned short* av1_bf  = (unsigned short*)alloc(ROWS * An * 2);
  float* ahA  = (float*)alloc(ROWS * 4);
  float* ahB  = (float*)alloc(ROWS * 4);
  float* ah1  = (float*)alloc(ROWS * 4);
  float* scA  = (float*)alloc(ROWS * 4);
  float* scB  = (float*)alloc(ROWS * 4);
  float* sc1  = (float*)alloc(ROWS * 4);
  float* res0 = (float*)alloc((size_t)Bn * Rn * 4);
  float* res1 = (float*)alloc((size_t)Bn * Rn * 4);
  float* nh   = (float*)alloc((size_t)Bn * Rn * 4);
  float* bsum = (float*)alloc((size_t)Gn * 4);
  float* sums = (float*)alloc((size_t)Bn * Gn * 4);

  const dim3 blk(256);

  // ---- att conversion (pure BW) + small packs
  f2b_copy<<<dim3(50176), blk, 0, stream>>>(att, att_bf, ROWS * Rn);
  pack_wpad<<<dim3(112), blk, 0, stream>>>(Wa2a, Wa2a1, Wpad);
  f2b_copy<<<dim3(49), blk, 0, stream>>>(Wh2a,  wh2a_bf,  (long)An * Rn);
  f2b_copy<<<dim3(49), blk, 0, stream>>>(Wh2a1, wh2a1_bf, (long)An * Rn);
  f2b_copy<<<dim3(256), blk, 0, stream>>>(prev_h0, h0_bf, (long)Bn * Rn);
  f2b_copy<<<dim3(256), blk, 0, stream>>>(prev_h1, h1_bf, (long)Bn * Rn);
  pack_w<<<dim3(6144), blk, 0, stream>>>(Wi2h, Wh2h, Wa2h, W2);
  bias3<<<dim3(Gn / 256), blk, 0, stream>>>(bi2h, bh2h, ba2h, bsum, Gn);

  // ---- ah projections for both layers' first attends
  gemm_bf<<<dim3(2, Bn / 128), blk, 0, stream>>>(h0_bf, wh2a_bf, bh2a, ahA, An, Rn, An);
  gemm_bf<<<dim3(2, Bn / 128), blk, 0, stream>>>(h1_bf, wh2a_bf, bh2a, ahB, An, Rn, An);

  // ---- fused dual projection: av0+dual score, av1 cache (one att_bf pass)
  av_both<<<dim3((int)(ROWS / 128)), dim3(512), 0, stream>>>(
      att_bf, Wpad, ba2a, ba2a1, Wd2d, ahA, ahB, scA, scB, av1_bf);
  wsum2<true><<<dim3(Bn / 2), blk, 0, stream>>>(att_bf, scA, scB, (const float*)nullptr, res0, res1);

  // ---- layer 0 LSTM
  pack_x<<<dim3(768), blk, 0, stream>>>(x, (const float*)nullptr, prev_h0, res0, X2);
  gemm_gate<<<dim3(512), blk, 0, stream>>>(X2, W2, bsum, sums);
  gates_pw<<<dim3(Bn * Rn / 256), blk, 0, stream>>>(sums, prev_c0, out + 0, nh, nh_bf);

  // ---- layer 0 second attend -> top_h0
  gemm_bf<<<dim3(2, Bn / 128), blk, 0, stream>>>(nh_bf, wh2a1_bf, bh2a1, ah1, An, Rn, An);
  score1<<<dim3((int)(ROWS / 4)), blk, 0, stream>>>(av1_bf, ah1, Wd2d1, sc1);
  wsum2<false><<<dim3(Bn / 2), blk, 0, stream>>>(att_bf, sc1, (const float*)nullptr, nh,
                                                 out + (long)Bn * Rn, (float*)nullptr);

  // ---- layer 1 LSTM (xt = x + top_h0)
  pack_x<<<dim3(768), blk, 0, stream>>>(x, out + (long)Bn * Rn, prev_h1, res1, X2);
  gemm_gate<<<dim3(512), blk, 0, stream>>>(X2, W2, bsum, sums);
  gates_pw<<<dim3(Bn * Rn / 256), blk, 0, stream>>>(sums, prev_c1, out + 2 * (long)Bn * Rn, nh, nh_bf);

  // ---- layer 1 second attend -> top_h1
  gemm_bf<<<dim3(2, Bn / 128), blk, 0, stream>>>(nh_bf, wh2a1_bf, bh2a1, ah1, An, Rn, An);
  score1<<<dim3((int)(ROWS / 4)), blk, 0, stream>>>(av1_bf, ah1, Wd2d1, sc1);
  wsum2<false><<<dim3(Bn / 2), blk, 0, stream>>>(att_bf, sc1, (const float*)nullptr, nh,
                                                 out + 3 * (long)Bn * Rn, (float*)nullptr);
}

// Round 6
// 714.541 us; speedup vs baseline: 1.0716x; 1.0716x over previous
//
#include <hip/hip_runtime.h>
#include <math.h>

typedef __attribute__((ext_vector_type(8))) unsigned short ushort8_t;
typedef __attribute__((ext_vector_type(8))) short bf16x8;
typedef __attribute__((ext_vector_type(4))) float f32x4;

namespace {

constexpr int Bn = 1024;
constexpr int Rn = 512;
constexpr int An = 196;
constexpr int Gn = 8192;     // P*4R
constexpr int Kcat = 1536;   // 3*R
constexpr int NP = 224;      // padded att cols per set (14 frags)
constexpr long ROWS = (long)Bn * An;  // 200704

__device__ __forceinline__ float b2f(unsigned short u) {
  union { unsigned int i; float f; } v; v.i = ((unsigned int)u) << 16; return v.f;
}
__device__ __forceinline__ unsigned short f2b(float f) {
  union { float f; unsigned int i; } v; v.f = f;
  unsigned int r = v.i + 0x7fffu + ((v.i >> 16) & 1u);
  return (unsigned short)(r >> 16);
}
__device__ __forceinline__ float sigmf(float x) {
  return __builtin_amdgcn_rcpf(1.f + __expf(-x));
}
__device__ __forceinline__ float tanhf_fast(float x) {
  const float e = __expf(2.f * x);
  return 1.f - 2.f * __builtin_amdgcn_rcpf(e + 1.f);
}

// ---- f32 -> bf16 copy, 8 elems/thread
__global__ __launch_bounds__(256)
void f2b_copy(const float* __restrict__ src, unsigned short* __restrict__ dst, long n)
{
  long i = ((long)blockIdx.x * 256 + threadIdx.x) * 8;
  const long stride = (long)gridDim.x * 256 * 8;
  for (; i + 8 <= n; i += stride) {
    float4 a = *(const float4*)(src + i);
    float4 b = *(const float4*)(src + i + 4);
    ushort8_t o;
    o[0] = f2b(a.x); o[1] = f2b(a.y); o[2] = f2b(a.z); o[3] = f2b(a.w);
    o[4] = f2b(b.x); o[5] = f2b(b.y); o[6] = f2b(b.z); o[7] = f2b(b.w);
    *(ushort8_t*)(dst + i) = o;
  }
}

// ---- pad+convert attention weights: Wp[2][NP][512] from Wa0/Wa1 [196][512]
__global__ __launch_bounds__(256)
void pack_wpad(const float* __restrict__ Wa0, const float* __restrict__ Wa1,
               unsigned short* __restrict__ Wp)
{
  long i = ((long)blockIdx.x * 256 + threadIdx.x) * 8;
  if (i >= 2L * NP * 512) return;
  const int set = (int)(i / (NP * 512));
  const int rem = (int)(i % (NP * 512));
  const int row = rem / 512, k = rem % 512;
  ushort8_t o;
  if (row < An) {
    const float* s = (set ? Wa1 : Wa0) + (long)row * 512 + k;
    float4 a = *(const float4*)s, b = *(const float4*)(s + 4);
    o[0] = f2b(a.x); o[1] = f2b(a.y); o[2] = f2b(a.z); o[3] = f2b(a.w);
    o[4] = f2b(b.x); o[5] = f2b(b.y); o[6] = f2b(b.z); o[7] = f2b(b.w);
  } else {
    o = ushort8_t{0,0,0,0,0,0,0,0};
  }
  *(ushort8_t*)(Wp + i) = o;
}

// ---- concat gate weights [8192][1536] bf16: [Wi | Wh | Wa]
__global__ __launch_bounds__(256)
void pack_w(const float* __restrict__ Wi, const float* __restrict__ Wh,
            const float* __restrict__ Wa, unsigned short* __restrict__ W2)
{
  long i = ((long)blockIdx.x * 256 + threadIdx.x) * 8;
  if (i >= (long)Gn * Kcat) return;
  const int g = (int)(i / Kcat);
  const int k = (int)(i % Kcat);
  const float* src = (k < 512) ? Wi + (long)g * 512 + k
                   : (k < 1024) ? Wh + (long)g * 512 + (k - 512)
                   : Wa + (long)g * 512 + (k - 1024);
  float4 a = *(const float4*)src;
  float4 b = *(const float4*)(src + 4);
  ushort8_t o;
  o[0] = f2b(a.x); o[1] = f2b(a.y); o[2] = f2b(a.z); o[3] = f2b(a.w);
  o[4] = f2b(b.x); o[5] = f2b(b.y); o[6] = f2b(b.z); o[7] = f2b(b.w);
  *(ushort8_t*)(W2 + i) = o;
}

// ---- concat gate inputs [1024][1536] bf16: [xa(+xb) | h | a]
__global__ __launch_bounds__(256)
void pack_x(const float* __restrict__ xa, const float* __restrict__ xb,
            const float* __restrict__ h, const float* __restrict__ a,
            unsigned short* __restrict__ X2)
{
  long i = ((long)blockIdx.x * 256 + threadIdx.x) * 8;
  if (i >= (long)Bn * Kcat) return;
  const int b = (int)(i / Kcat);
  const int k = (int)(i % Kcat);
  ushort8_t o;
  if (k < 512) {
    const float* s = xa + (long)b * 512 + k;
    float4 v0 = *(const float4*)s, v1 = *(const float4*)(s + 4);
    if (xb) {
      const float* s2 = xb + (long)b * 512 + k;
      float4 w0 = *(const float4*)s2, w1 = *(const float4*)(s2 + 4);
      v0.x += w0.x; v0.y += w0.y; v0.z += w0.z; v0.w += w0.w;
      v1.x += w1.x; v1.y += w1.y; v1.z += w1.z; v1.w += w1.w;
    }
    o[0] = f2b(v0.x); o[1] = f2b(v0.y); o[2] = f2b(v0.z); o[3] = f2b(v0.w);
    o[4] = f2b(v1.x); o[5] = f2b(v1.y); o[6] = f2b(v1.z); o[7] = f2b(v1.w);
  } else {
    const float* s = (k < 1024) ? h + (long)b * 512 + (k - 512)
                                : a + (long)b * 512 + (k - 1024);
    float4 v0 = *(const float4*)s, v1 = *(const float4*)(s + 4);
    o[0] = f2b(v0.x); o[1] = f2b(v0.y); o[2] = f2b(v0.z); o[3] = f2b(v0.w);
    o[4] = f2b(v1.x); o[5] = f2b(v1.y); o[6] = f2b(v1.z); o[7] = f2b(v1.w);
  }
  *(ushort8_t*)(X2 + i) = o;
}

// ---- column-split att-projection, m97-style gload_lds staging.
// grid (ROWS/128, 2); blockIdx.y = weight set.
// set0: T = att_bf * Wa2a_pad^T, dual-score epilogue -> s0,s1
// set1: T = att_bf * Wa2a1_pad^T, av1(+bias) bf16 -> av_out
// 512 threads = 8 waves, wave grid 4x2; tile 128 x 224; acc[2][7].
__global__ __launch_bounds__(512, 4)
void av_cs(const unsigned short* __restrict__ A,
           const unsigned short* __restrict__ Wpad,
           const float* __restrict__ b0vec, const float* __restrict__ b1vec,
           const float* __restrict__ Wd,
           const float* __restrict__ ah0, const float* __restrict__ ah1,
           float* __restrict__ s0, float* __restrict__ s1,
           unsigned short* __restrict__ av_out)
{
  __shared__ unsigned short As[128 * 32];
  __shared__ unsigned short Bs[224 * 32];
  __shared__ float wds[NP], bas[NP];
  __shared__ float ahAs[128], ahBs[128];
  __shared__ float sbA[128], sbB[128];

  const int tid = threadIdx.x;
  const int lane = tid & 63, w = tid >> 6;
  const int wr = w >> 1, wc = w & 1;        // 4 x 2 wave grid
  const int fr = lane & 15, q = lane >> 4;
  const long row0 = (long)blockIdx.x * 128;
  const int set = blockIdx.y;

  if (set == 0) {
    if (tid < NP) {
      wds[tid] = (tid < An) ? Wd[tid] : 0.f;
      bas[tid] = (tid < An) ? b0vec[tid] : 0.f;
    }
    if (tid >= 256 && tid < 384) ahAs[tid - 256] = ah0[row0 + tid - 256];
    if (tid >= 384)              ahBs[tid - 384] = ah1[row0 + tid - 384];
  } else {
    if (tid < NP) bas[tid] = (tid < An) ? b1vec[tid] : 0.f;
  }

  const unsigned short* Ab = A + row0 * 512;
  const unsigned short* Bb = Wpad + (long)set * NP * 512;

  f32x4 acc[2][7] = {};

  const int grow = lane >> 2;        // row within 16-row group
  const int gchk = (lane & 3) * 8;   // 16B chunk (shorts)

  for (int kt = 0; kt < 512; kt += 32) {
    // A: wave w stages group w (16 rows x 32 cols)
    {
      const unsigned short* src = Ab + (long)(w * 16 + grow) * 512 + gchk + kt;
      __builtin_amdgcn_global_load_lds(
          (const __attribute__((address_space(1))) unsigned int*)src,
          (__attribute__((address_space(3))) unsigned int*)(As + w * 512), 16, 0, 0);
    }
    // B: wave w stages group w; waves 0..5 also stage group w+8
    {
      const unsigned short* src = Bb + (long)(w * 16 + grow) * 512 + gchk + kt;
      __builtin_amdgcn_global_load_lds(
          (const __attribute__((address_space(1))) unsigned int*)src,
          (__attribute__((address_space(3))) unsigned int*)(Bs + w * 512), 16, 0, 0);
    }
    if (w < 6) {
      const unsigned short* src = Bb + (long)((w + 8) * 16 + grow) * 512 + gchk + kt;
      __builtin_amdgcn_global_load_lds(
          (const __attribute__((address_space(1))) unsigned int*)src,
          (__attribute__((address_space(3))) unsigned int*)(Bs + (w + 8) * 512), 16, 0, 0);
    }
    __syncthreads();
    bf16x8 af[2], bfr[7];
#pragma unroll
    for (int m = 0; m < 2; ++m)
      af[m] = *(const bf16x8*)&As[(wr * 32 + m * 16 + fr) * 32 + q * 8];
#pragma unroll
    for (int n = 0; n < 7; ++n)
      bfr[n] = *(const bf16x8*)&Bs[(wc * 112 + n * 16 + fr) * 32 + q * 8];
#pragma unroll
    for (int m = 0; m < 2; ++m)
#pragma unroll
      for (int n = 0; n < 7; ++n)
        acc[m][n] = __builtin_amdgcn_mfma_f32_16x16x32_bf16(af[m], bfr[n], acc[m][n], 0, 0, 0);
    __syncthreads();
  }

  if (set == 0) {
    float pA[2][4], pB[2][4];
#pragma unroll
    for (int m = 0; m < 2; ++m)
#pragma unroll
      for (int j = 0; j < 4; ++j) { pA[m][j] = 0.f; pB[m][j] = 0.f; }
#pragma unroll
    for (int n = 0; n < 7; ++n) {
      const int col = wc * 112 + n * 16 + fr;
      const float wd = wds[col];
      const float bv = bas[col];
#pragma unroll
      for (int m = 0; m < 2; ++m) {
#pragma unroll
        for (int j = 0; j < 4; ++j) {
          const int rl = wr * 32 + m * 16 + q * 4 + j;
          const float av = acc[m][n][j] + bv;
          pA[m][j] += wd * tanhf_fast(av + ahAs[rl]);
          pB[m][j] += wd * tanhf_fast(av + ahBs[rl]);
        }
      }
    }
#pragma unroll
    for (int m = 0; m < 2; ++m)
#pragma unroll
      for (int j = 0; j < 4; ++j) {
#pragma unroll
        for (int off = 1; off < 16; off <<= 1) {
          pA[m][j] += __shfl_xor(pA[m][j], off);
          pB[m][j] += __shfl_xor(pB[m][j], off);
        }
      }
    __syncthreads();
    if (wc == 0 && fr == 0) {
#pragma unroll
      for (int m = 0; m < 2; ++m)
#pragma unroll
        for (int j = 0; j < 4; ++j) {
          const int rl = wr * 32 + m * 16 + q * 4 + j;
          sbA[rl] = pA[m][j]; sbB[rl] = pB[m][j];
        }
    }
    __syncthreads();
    if (wc == 1 && fr == 0) {
#pragma unroll
      for (int m = 0; m < 2; ++m)
#pragma unroll
        for (int j = 0; j < 4; ++j) {
          const int rl = wr * 32 + m * 16 + q * 4 + j;
          sbA[rl] += pA[m][j]; sbB[rl] += pB[m][j];
        }
    }
    __syncthreads();
    if (tid < 128) {
      s0[row0 + tid] = sbA[tid];
      s1[row0 + tid] = sbB[tid];
    }
  } else {
#pragma unroll
    for (int n = 0; n < 7; ++n) {
      const int col = wc * 112 + n * 16 + fr;
      if (col >= An) continue;
      const float bv = bas[col];
#pragma unroll
      for (int m = 0; m < 2; ++m) {
#pragma unroll
        for (int j = 0; j < 4; ++j) {
          const long row = row0 + wr * 32 + m * 16 + q * 4 + j;
          av_out[row * An + col] = f2b(acc[m][n][j] + bv);
        }
      }
    }
  }
}

// ---- gate GEMM: C[1024,8192] = X2[1024,1536] * W2[8192,1536]^T + bias
__global__ __launch_bounds__(256)
void gemm_gate(const unsigned short* __restrict__ A, const unsigned short* __restrict__ Bm,
               const float* __restrict__ bias, float* __restrict__ C)
{
  __shared__ unsigned short As[128 * 32];
  __shared__ unsigned short Bs[128 * 32];
  const int tid = threadIdx.x;
  const int lane = tid & 63, w = tid >> 6;
  int bid = blockIdx.x;
  bid = (bid & 7) * (gridDim.x >> 3) + (bid >> 3);   // XCD-bijective (512 % 8 == 0)
  const int bx = bid & 63;          // 64 col tiles
  const int by = bid >> 6;          // 8 row tiles
  const long row0 = (long)by * 128;
  const long col0 = (long)bx * 128;
  const int wr = w >> 1, wc = w & 1;
  const int fr = lane & 15, q = lane >> 4;
  const int srow = lane >> 2, schk = lane & 3;

  f32x4 acc[4][4] = {};
  const unsigned short* A0 = A + row0 * Kcat + schk * 8;
  const unsigned short* B0 = Bm + col0 * Kcat + schk * 8;

  for (int kt = 0; kt < Kcat; kt += 32) {
#pragma unroll
    for (int i = 0; i < 2; ++i) {
      const int rr = (w * 2 + i) * 16 + srow;
      __builtin_amdgcn_global_load_lds(
          (const __attribute__((address_space(1))) unsigned int*)(A0 + (long)rr * Kcat + kt),
          (__attribute__((address_space(3))) unsigned int*)(As + (w * 2 + i) * 512),
          16, 0, 0);
      __builtin_amdgcn_global_load_lds(
          (const __attribute__((address_space(1))) unsigned int*)(B0 + (long)rr * Kcat + kt),
          (__attribute__((address_space(3))) unsigned int*)(Bs + (w * 2 + i) * 512),
          16, 0, 0);
    }
    __syncthreads();
    bf16x8 af[4], bfr[4];
#pragma unroll
    for (int m = 0; m < 4; ++m)
      af[m] = *(const bf16x8*)&As[(wr * 64 + m * 16 + fr) * 32 + q * 8];
#pragma unroll
    for (int n = 0; n < 4; ++n)
      bfr[n] = *(const bf16x8*)&Bs[(wc * 64 + n * 16 + fr) * 32 + q * 8];
#pragma unroll
    for (int m = 0; m < 4; ++m)
#pragma unroll
      for (int n = 0; n < 4; ++n)
        acc[m][n] = __builtin_amdgcn_mfma_f32_16x16x32_bf16(af[m], bfr[n], acc[m][n], 0, 0, 0);
    __syncthreads();
  }

  const int crow = wr * 64 + q * 4;
  const int ccol = wc * 64 + fr;
#pragma unroll
  for (int n = 0; n < 4; ++n) {
    const int col = (int)col0 + ccol + n * 16;
    const float bv = bias[col];
#pragma unroll
    for (int m = 0; m < 4; ++m) {
      const long rb = row0 + crow + m * 16;
#pragma unroll
      for (int j = 0; j < 4; ++j)
        C[(rb + j) * (long)Gn + col] = acc[m][n][j] + bv;
    }
  }
}

// ---- bf16 MFMA GEMM (small, ragged N): C[M,N] = A*B^T + bias, C f32
__global__ __launch_bounds__(256)
void gemm_bf(const unsigned short* __restrict__ A, const unsigned short* __restrict__ Bm,
             const float* __restrict__ bias, float* __restrict__ C,
             int N, int K, int ldc)
{
  constexpr int LDP = 56;
  __shared__ unsigned short As[128 * LDP];
  __shared__ unsigned short Bs[128 * LDP];
  const int tid = threadIdx.x;
  const long row0 = (long)blockIdx.y * 128;
  const int col0 = blockIdx.x * 128;
  const int wid = tid >> 6, lane = tid & 63;
  const int wr = wid >> 1, wc = wid & 1;
  const int fr = lane & 15, kg = (lane >> 4) * 8;

  f32x4 acc[4][4] = {};

  const int srow = tid >> 1;
  const int skh = tid & 1;
  const unsigned short* Ap = A + (row0 + srow) * (long)K + skh * 16;
  const int bcol = col0 + srow;
  const unsigned short* Bp = Bm + (long)(bcol < N ? bcol : N - 1) * K + skh * 16;

  ushort8_t a0 = *(const ushort8_t*)(Ap);
  ushort8_t a1 = *(const ushort8_t*)(Ap + 8);
  ushort8_t b0 = *(const ushort8_t*)(Bp);
  ushort8_t b1 = *(const ushort8_t*)(Bp + 8);

  const int sw = srow * LDP + skh * 16;
  for (int kt = 0; kt < K; kt += 32) {
    *(ushort8_t*)&As[sw] = a0;
    *(ushort8_t*)&As[sw + 8] = a1;
    *(ushort8_t*)&Bs[sw] = b0;
    *(ushort8_t*)&Bs[sw + 8] = b1;
    if (kt + 32 < K) {
      a0 = *(const ushort8_t*)(Ap + kt + 32);
      a1 = *(const ushort8_t*)(Ap + kt + 40);
      b0 = *(const ushort8_t*)(Bp + kt + 32);
      b1 = *(const ushort8_t*)(Bp + kt + 40);
    }
    __syncthreads();
    bf16x8 af[4], bfr[4];
#pragma unroll
    for (int m = 0; m < 4; ++m)
      af[m] = *(const bf16x8*)&As[(wr * 64 + m * 16 + fr) * LDP + kg];
#pragma unroll
    for (int n = 0; n < 4; ++n)
      bfr[n] = *(const bf16x8*)&Bs[(wc * 64 + n * 16 + fr) * LDP + kg];
#pragma unroll
    for (int m = 0; m < 4; ++m)
#pragma unroll
      for (int n = 0; n < 4; ++n)
        acc[m][n] = __builtin_amdgcn_mfma_f32_16x16x32_bf16(af[m], bfr[n], acc[m][n], 0, 0, 0);
    __syncthreads();
  }

  const int crow = wr * 64 + (lane >> 4) * 4;
  const int ccol = wc * 64 + fr;
#pragma unroll
  for (int n = 0; n < 4; ++n) {
    const int col = col0 + ccol + n * 16;
    if (col >= N) continue;
    const float bv = bias ? bias[col] : 0.f;
#pragma unroll
    for (int m = 0; m < 4; ++m) {
      const long rb = row0 + crow + m * 16;
#pragma unroll
      for (int j = 0; j < 4; ++j)
        C[(rb + j) * (long)ldc + col] = acc[m][n][j] + bv;
    }
  }
}

// ---- single score over cached bf16 av (raw; softmax in wsum)
__global__ __launch_bounds__(256)
void score1(const unsigned short* __restrict__ av, const float* __restrict__ ah,
            const float* __restrict__ Wd, float* __restrict__ s0)
{
  const int row = blockIdx.x * 4 + (threadIdx.x >> 6);
  const int lane = threadIdx.x & 63;
  const unsigned short* avp = av + (long)row * An;
  const float A0 = ah[row];
  float v0 = 0.f;
  for (int a = lane; a < An; a += 64)
    v0 += Wd[a] * tanhf_fast(b2f(avp[a]) + A0);
#pragma unroll
  for (int o = 32; o; o >>= 1) v0 += __shfl_down(v0, o);
  if (lane == 0) s0[row] = v0;
}

// ---- softmax (in-block) + weighted sum over bf16 att; 2 batches/block
template<bool DUAL>
__global__ __launch_bounds__(256)
void wsum2(const unsigned short* __restrict__ att,
           const float* __restrict__ w0, const float* __restrict__ w1,
           const float* __restrict__ add0,
           float* __restrict__ o0, float* __restrict__ o1)
{
  const int half = threadIdx.x >> 7;
  const int b = blockIdx.x * 2 + half;
  const int t = threadIdx.x & 127;
  const int wv = t >> 6;
  __shared__ float ws0[2][An], ws1[2][An];
  __shared__ float redm[2][2][2], redsum[2][2][2];

  const float r0a = w0[(long)b * An + t];
  const float r0b = (t + 128 < An) ? w0[(long)b * An + t + 128] : -3.0e38f;
  float r1a = -3.0e38f, r1b = -3.0e38f;
  if (DUAL) {
    r1a = w1[(long)b * An + t];
    r1b = (t + 128 < An) ? w1[(long)b * An + t + 128] : -3.0e38f;
  }
  float m0 = fmaxf(r0a, r0b), m1 = fmaxf(r1a, r1b);
#pragma unroll
  for (int o = 32; o; o >>= 1) {
    m0 = fmaxf(m0, __shfl_xor(m0, o));
    if (DUAL) m1 = fmaxf(m1, __shfl_xor(m1, o));
  }
  if ((t & 63) == 0) { redm[0][half][wv] = m0; if (DUAL) redm[1][half][wv] = m1; }
  __syncthreads();
  m0 = fmaxf(redm[0][half][0], redm[0][half][1]);
  if (DUAL) m1 = fmaxf(redm[1][half][0], redm[1][half][1]);
  const float e0a = __expf(r0a - m0);
  const float e0b = (t + 128 < An) ? __expf(r0b - m0) : 0.f;
  float sl0 = e0a + e0b, sl1 = 0.f;
  float e1a = 0.f, e1b = 0.f;
  if (DUAL) {
    e1a = __expf(r1a - m1);
    e1b = (t + 128 < An) ? __expf(r1b - m1) : 0.f;
    sl1 = e1a + e1b;
  }
#pragma unroll
  for (int o = 32; o; o >>= 1) {
    sl0 += __shfl_xor(sl0, o);
    if (DUAL) sl1 += __shfl_xor(sl1, o);
  }
  if ((t & 63) == 0) { redsum[0][half][wv] = sl0; if (DUAL) redsum[1][half][wv] = sl1; }
  __syncthreads();
  const float inv0 = __builtin_amdgcn_rcpf(redsum[0][half][0] + redsum[0][half][1]);
  ws0[half][t] = e0a * inv0;
  if (t + 128 < An) ws0[half][t + 128] = e0b * inv0;
  if (DUAL) {
    const float inv1 = __builtin_amdgcn_rcpf(redsum[1][half][0] + redsum[1][half][1]);
    ws1[half][t] = e1a * inv1;
    if (t + 128 < An) ws1[half][t + 128] = e1b * inv1;
  }
  __syncthreads();

  const unsigned short* ap = att + (long)b * An * Rn + t * 4;
  float a00 = 0, a01 = 0, a02 = 0, a03 = 0;
  float a10 = 0, a11 = 0, a12 = 0, a13 = 0;
  for (int s = 0; s < An; ++s) {
    ushort4 u = *(const ushort4*)(ap + (long)s * Rn);
    const float f0 = b2f(u.x), f1 = b2f(u.y), f2 = b2f(u.z), f3 = b2f(u.w);
    const float v0 = ws0[half][s];
    a00 = fmaf(f0, v0, a00); a01 = fmaf(f1, v0, a01);
    a02 = fmaf(f2, v0, a02); a03 = fmaf(f3, v0, a03);
    if (DUAL) {
      const float v1 = ws1[half][s];
      a10 = fmaf(f0, v1, a10); a11 = fmaf(f1, v1, a11);
      a12 = fmaf(f2, v1, a12); a13 = fmaf(f3, v1, a13);
    }
  }
  const long base = (long)b * Rn + t * 4;
  if (add0) {
    float4 ad = *(const float4*)(add0 + base);
    a00 += ad.x; a01 += ad.y; a02 += ad.z; a03 += ad.w;
  }
  *(float4*)(o0 + base) = make_float4(a00, a01, a02, a03);
  if (DUAL) *(float4*)(o1 + base) = make_float4(a10, a11, a12, a13);
}

// ---- LSTM pointwise over P=4 parallels
__global__ __launch_bounds__(256)
void gates_pw(const float* __restrict__ sums, const float* __restrict__ prev_c,
              float* __restrict__ out_c, float* __restrict__ nh,
              unsigned short* __restrict__ nh_bf)
{
  const int i = blockIdx.x * 256 + threadIdx.x;
  const int b = i >> 9;
  const int r = i & 511;
  const float c = prev_c[i];
  float aC = 0.f, aH = 0.f;
#pragma unroll
  for (int p = 0; p < 4; ++p) {
    const float* sp = sums + (long)b * Gn + p * 2048 + r;
    const float ig = sigmf(sp[0]);
    const float fg = sigmf(sp[512]);
    const float og = sigmf(sp[1024]);
    const float it = tanhf_fast(sp[1536]);
    const float nc = fmaf(fg, c, ig * it);
    aC += nc;
    aH = fmaf(og, tanhf_fast(nc), aH);
  }
  out_c[i] = aC * 0.25f;
  const float hv = aH * 0.25f;
  nh[i] = hv;
  nh_bf[i] = f2b(hv);
}

__global__ __launch_bounds__(256)
void bias3(const float* __restrict__ a, const float* __restrict__ b,
           const float* __restrict__ c, float* __restrict__ o, int n)
{
  const int i = blockIdx.x * 256 + threadIdx.x;
  if (i < n) o[i] = a[i] + b[i] + c[i];
}

} // namespace

extern "C" void kernel_launch(void* const* d_in, const int* in_sizes, int n_in,
                              void* d_out, int out_size, void* d_ws, size_t ws_size,
                              hipStream_t stream)
{
  const float* x      = (const float*)d_in[0];
  const float* att    = (const float*)d_in[1];
  const float* inputs = (const float*)d_in[2];
  const float* Wa2a   = (const float*)d_in[3];
  const float* ba2a   = (const float*)d_in[4];
  const float* Wh2a   = (const float*)d_in[5];
  const float* bh2a   = (const float*)d_in[6];
  const float* Wd2d   = (const float*)d_in[7];
  const float* Wa2a1  = (const float*)d_in[9];
  const float* ba2a1  = (const float*)d_in[10];
  const float* Wh2a1  = (const float*)d_in[11];
  const float* bh2a1  = (const float*)d_in[12];
  const float* Wd2d1  = (const float*)d_in[13];
  const float* Wi2h   = (const float*)d_in[15];
  const float* bi2h   = (const float*)d_in[16];
  const float* Wh2h   = (const float*)d_in[17];
  const float* bh2h   = (const float*)d_in[18];
  const float* Wa2h   = (const float*)d_in[19];
  const float* ba2h   = (const float*)d_in[20];
  (void)in_sizes; (void)n_in; (void)out_size; (void)ws_size;

  float* out = (float*)d_out;
  const float* prev_c0 = inputs + 0 * (long)Bn * Rn;
  const float* prev_h0 = inputs + 1 * (long)Bn * Rn;
  const float* prev_c1 = inputs + 2 * (long)Bn * Rn;
  const float* prev_h1 = inputs + 3 * (long)Bn * Rn;

  char* wsp = (char*)d_ws;
  size_t off = 0;
  auto alloc = [&](size_t bytes) -> void* {
    void* p = wsp + off;
    off += (bytes + 1023) & ~(size_t)1023;
    return p;
  };
  unsigned short* att_bf  = (unsigned short*)alloc(ROWS * Rn * 2);
  unsigned short* W2      = (unsigned short*)alloc((size_t)Gn * Kcat * 2);
  unsigned short* Wpad    = (unsigned short*)alloc((size_t)2 * NP * Rn * 2);
  unsigned short* wh2a_bf = (unsigned short*)alloc((size_t)An * Rn * 2);
  unsigned short* wh2a1_bf= (unsigned short*)alloc((size_t)An * Rn * 2);
  unsigned short* h01_bf  = (unsigned short*)alloc((size_t)2 * Bn * Rn * 2);
  unsigned short* nh_bf   = (unsigned short*)alloc((size_t)Bn * Rn * 2);
  unsigned short* X2      = (unsigned short*)alloc((size_t)Bn * Kcat * 2);
  unsigned short* av1_bf  = (unsigned short*)alloc(ROWS * An * 2);
  float* ahAB = (float*)alloc((size_t)2 * ROWS * 4);
  float* ah1  = (float*)alloc(ROWS * 4);
  float* scA  = (float*)alloc(ROWS * 4);
  float* scB  = (float*)alloc(ROWS * 4);
  float* sc1  = (float*)alloc(ROWS * 4);
  float* res0 = (float*)alloc((size_t)Bn * Rn * 4);
  float* res1 = (float*)alloc((size_t)Bn * Rn * 4);
  float* nh   = (float*)alloc((size_t)Bn * Rn * 4);
  float* bsum = (float*)alloc((size_t)Gn * 4);
  float* sums = (float*)alloc((size_t)Bn * Gn * 4);

  float* ahA = ahAB;
  float* ahB = ahAB + ROWS;

  const dim3 blk(256);

  // ---- att conversion (pure BW) + small packs
  f2b_copy<<<dim3(50176), blk, 0, stream>>>(att, att_bf, ROWS * Rn);
  pack_wpad<<<dim3(112), blk, 0, stream>>>(Wa2a, Wa2a1, Wpad);
  f2b_copy<<<dim3(49), blk, 0, stream>>>(Wh2a,  wh2a_bf,  (long)An * Rn);
  f2b_copy<<<dim3(49), blk, 0, stream>>>(Wh2a1, wh2a1_bf, (long)An * Rn);
  f2b_copy<<<dim3(256), blk, 0, stream>>>(prev_h0, h01_bf, (long)Bn * Rn);
  f2b_copy<<<dim3(256), blk, 0, stream>>>(prev_h1, h01_bf + (long)Bn * Rn, (long)Bn * Rn);
  pack_w<<<dim3(6144), blk, 0, stream>>>(Wi2h, Wh2h, Wa2h, W2);
  bias3<<<dim3(Gn / 256), blk, 0, stream>>>(bi2h, bh2h, ba2h, bsum, Gn);

  // ---- ah projections, both layers in one GEMM (M = 2048)
  gemm_bf<<<dim3(2, 16), blk, 0, stream>>>(h01_bf, wh2a_bf, bh2a, ahA, An, Rn, An);

  // ---- column-split projection: set0 dual-score + set1 av1 cache
  av_cs<<<dim3((int)(ROWS / 128), 2), dim3(512), 0, stream>>>(
      att_bf, Wpad, ba2a, ba2a1, Wd2d, ahA, ahB, scA, scB, av1_bf);
  wsum2<true><<<dim3(Bn / 2), blk, 0, stream>>>(att_bf, scA, scB, (const float*)nullptr, res0, res1);

  // ---- layer 0 LSTM
  pack_x<<<dim3(768), blk, 0, stream>>>(x, (const float*)nullptr, prev_h0, res0, X2);
  gemm_gate<<<dim3(512), blk, 0, stream>>>(X2, W2, bsum, sums);
  gates_pw<<<dim3(Bn * Rn / 256), blk, 0, stream>>>(sums, prev_c0, out + 0, nh, nh_bf);

  // ---- layer 0 second attend -> top_h0
  gemm_bf<<<dim3(2, Bn / 128), blk, 0, stream>>>(nh_bf, wh2a1_bf, bh2a1, ah1, An, Rn, An);
  score1<<<dim3((int)(ROWS / 4)), blk, 0, stream>>>(av1_bf, ah1, Wd2d1, sc1);
  wsum2<false><<<dim3(Bn / 2), blk, 0, stream>>>(att_bf, sc1, (const float*)nullptr, nh,
                                                 out + (long)Bn * Rn, (float*)nullptr);

  // ---- layer 1 LSTM (xt = x + top_h0)
  pack_x<<<dim3(768), blk, 0, stream>>>(x, out + (long)Bn * Rn, prev_h1, res1, X2);
  gemm_gate<<<dim3(512), blk, 0, stream>>>(X2, W2, bsum, sums);
  gates_pw<<<dim3(Bn * Rn / 256), blk, 0, stream>>>(sums, prev_c1, out + 2 * (long)Bn * Rn, nh, nh_bf);

  // ---- layer 1 second attend -> top_h1
  gemm_bf<<<dim3(2, Bn / 128), blk, 0, stream>>>(nh_bf, wh2a1_bf, bh2a1, ah1, An, Rn, An);
  score1<<<dim3((int)(ROWS / 4)), blk, 0, stream>>>(av1_bf, ah1, Wd2d1, sc1);
  wsum2<false><<<dim3(Bn / 2), blk, 0, stream>>>(att_bf, sc1, (const float*)nullptr, nh,
                                                 out + 3 * (long)Bn * Rn, (float*)nullptr);
}